// Round 20
// baseline (208.445 us; speedup 1.0000x reference)
//
#include <hip/hip_runtime.h>
#include <hip/hip_bf16.h>

typedef float f32x4 __attribute__((ext_vector_type(4)));
typedef __bf16 bf16x8 __attribute__((ext_vector_type(8)));
typedef __bf16 bf16x4 __attribute__((ext_vector_type(4)));
typedef unsigned short ushort4v __attribute__((ext_vector_type(4)));
typedef unsigned short ushort8v __attribute__((ext_vector_type(8)));

#define MFMA16(a, b, c) __builtin_amdgcn_mfma_f32_16x16x32_bf16((a), (b), (c), 0, 0, 0)

__device__ __forceinline__ unsigned short f2bf(float f) {
    union { float f; unsigned int u; } v; v.f = f;
    unsigned int r = (v.u + 0x7fffu + ((v.u >> 16) & 1u)) >> 16;  // RNE
    return (unsigned short)r;
}
__device__ __forceinline__ int imin(int a, int b) { return a < b ? a : b; }
__device__ __forceinline__ float fexp2(float x) {  // raw v_exp_f32 (2^x)
    float r; asm("v_exp_f32 %0, %1" : "=v"(r) : "v"(x)); return r;
}

// LDS-only barrier: flush this wave's LDS ops, then s_barrier (no vmcnt drain).
__device__ __forceinline__ void ldsbar() {
    asm volatile("s_waitcnt lgkmcnt(0)" ::: "memory");
    __builtin_amdgcn_s_barrier();
}

// ---------------------------------------------------------------------------
// prep_w: W -> bf16 in MFMA-fragment order (round-15, measured good).
// ---------------------------------------------------------------------------
__global__ __launch_bounds__(256) void prep_w(const float* __restrict__ wq,
                                              const float* __restrict__ wk,
                                              const float* __restrict__ wv,
                                              unsigned short* __restrict__ Fqk,
                                              unsigned short* __restrict__ Fv)
{
    const int t = blockIdx.x * 256 + threadIdx.x;
    if (t < 8192) {
        const int lane = t & 63, kt = (t >> 6) & 15, ct = t >> 10;
        const int g = lane >> 4, li = lane & 15;
        const int c = ct * 16 + li;
        const int k0 = kt * 32 + g * 8;
        ushort8v u;
        if (c < 64) {
#pragma unroll
            for (int j = 0; j < 8; ++j) u[j] = f2bf(wq[(size_t)(k0 + j) * 64 + c]);
        } else {
#pragma unroll
            for (int j = 0; j < 8; ++j) u[j] = f2bf(wk[(size_t)(k0 + j) * 64 + (c - 64)]);
        }
        *(ushort8v*)&Fqk[(size_t)t * 8] = u;
    } else {
        const int t2 = t - 8192;
        const int lane = t2 & 63, kt = (t2 >> 6) & 15, ct = t2 >> 10;
        const int g = lane >> 4, li = lane & 15;
        const int c = ct * 16 + li;
        const int k0 = kt * 32 + g * 8;
        ushort8v u;
#pragma unroll
        for (int j = 0; j < 8; ++j) u[j] = f2bf(wv[(size_t)(k0 + j) * 512 + c]);
        *(ushort8v*)&Fv[(size_t)t2 * 8] = u;
    }
}

// ---------------------------------------------------------------------------
// Projection v2 (round-15, measured ~18-20 us): no B-LDS, A dbuf, 1 ldsbar/kt.
// ---------------------------------------------------------------------------
__global__ __launch_bounds__(512) void proj_kernel(const float* __restrict__ E,
        const unsigned short* __restrict__ Fqk, const unsigned short* __restrict__ Fv,
        const float* __restrict__ bq, const float* __restrict__ bk, const float* __restrict__ bv,
        unsigned short* __restrict__ Qb, unsigned short* __restrict__ Kb,
        unsigned short* __restrict__ Vt)
{
    __shared__ __align__(16) unsigned short Al[2][128][40];

    const int tid = threadIdx.x;
    const int w = tid >> 6, l = tid & 63, g = l >> 4, li = l & 15;
    const int wm = w >> 2, wn = w & 3;
    const int bx = blockIdx.x, by = blockIdx.y;
    const int row0 = bx * 128;
    const int arow = tid >> 2, ak = (tid & 3) * 8;
    const float* ebase = &E[(size_t)(row0 + arow) * 512 + ak];
    const float QSCALE = 0.125f * 1.4426950408889634f;  // 1/8 * log2(e)

#define LOAD_E(kt, dst)                                                          \
    {                                                                            \
        const float* ep = ebase + (kt) * 32;                                     \
        f32x4 v0 = *(const f32x4*)ep;                                            \
        f32x4 v1 = *(const f32x4*)(ep + 4);                                      \
        _Pragma("unroll")                                                        \
        for (int j = 0; j < 4; ++j) { dst[j] = f2bf(v0[j]); dst[4 + j] = f2bf(v1[j]); } \
    }

    if (by == 0) {
        f32x4 acc[4][2];
#pragma unroll
        for (int mb = 0; mb < 4; ++mb)
#pragma unroll
            for (int nb = 0; nb < 2; ++nb) acc[mb][nb] = (f32x4)0.0f;

        bf16x8 bw[2], bwn[2];
        {
            ushort8v e0; LOAD_E(0, e0);
            *(ushort8v*)&Al[0][arow][ak] = e0;
#pragma unroll
            for (int nb = 0; nb < 2; ++nb) {
                const int ct = wn * 2 + nb;
                bw[nb] = *(const bf16x8*)&Fqk[((size_t)(ct * 16 + 0) * 64 + l) * 8];
            }
        }
        ldsbar();

        for (int kt = 0; kt < 16; ++kt) {
            const int buf = kt & 1;
            ushort8v en;
            if (kt < 15) LOAD_E(kt + 1, en);
            const int ktn = imin(kt + 1, 15);
#pragma unroll
            for (int nb = 0; nb < 2; ++nb) {
                const int ct = wn * 2 + nb;
                bwn[nb] = *(const bf16x8*)&Fqk[((size_t)(ct * 16 + ktn) * 64 + l) * 8];
            }
            bf16x8 af[4];
#pragma unroll
            for (int mb = 0; mb < 4; ++mb)
                af[mb] = *(const bf16x8*)&Al[buf][wm * 64 + mb * 16 + li][8 * g];
#pragma unroll
            for (int mb = 0; mb < 4; ++mb)
#pragma unroll
                for (int nb = 0; nb < 2; ++nb) acc[mb][nb] = MFMA16(af[mb], bw[nb], acc[mb][nb]);
            if (kt < 15) *(ushort8v*)&Al[buf ^ 1][arow][ak] = en;
            ldsbar();
            bw[0] = bwn[0]; bw[1] = bwn[1];
        }

#pragma unroll
        for (int mb = 0; mb < 4; ++mb) {
#pragma unroll
            for (int nb = 0; nb < 2; ++nb) {
                const int coll = wn * 32 + nb * 16 + li;
                const int grow0 = row0 + wm * 64 + mb * 16 + 4 * g;
                if (coll < 64) {
                    const float bb = bq[coll];
#pragma unroll
                    for (int r = 0; r < 4; ++r)
                        Qb[(size_t)(grow0 + r) * 64 + coll] = f2bf((acc[mb][nb][r] + bb) * QSCALE);
                } else {
                    const float bb = bk[coll - 64];
#pragma unroll
                    for (int r = 0; r < 4; ++r)
                        Kb[(size_t)(grow0 + r) * 64 + (coll - 64)] = f2bf(acc[mb][nb][r] + bb);
                }
            }
        }
    } else {
        const int vy = by - 1;
        f32x4 acc[4][4];
#pragma unroll
        for (int mb = 0; mb < 4; ++mb)
#pragma unroll
            for (int nb = 0; nb < 4; ++nb) acc[mb][nb] = (f32x4)0.0f;

        bf16x8 bw[4], bwn[4];
        {
            ushort8v e0; LOAD_E(0, e0);
            *(ushort8v*)&Al[0][arow][ak] = e0;
#pragma unroll
            for (int nb = 0; nb < 4; ++nb) {
                const int ct = vy * 16 + wn * 4 + nb;
                bw[nb] = *(const bf16x8*)&Fv[((size_t)(ct * 16 + 0) * 64 + l) * 8];
            }
        }
        ldsbar();

        for (int kt = 0; kt < 16; ++kt) {
            const int buf = kt & 1;
            ushort8v en;
            if (kt < 15) LOAD_E(kt + 1, en);
            const int ktn = imin(kt + 1, 15);
#pragma unroll
            for (int nb = 0; nb < 4; ++nb) {
                const int ct = vy * 16 + wn * 4 + nb;
                bwn[nb] = *(const bf16x8*)&Fv[((size_t)(ct * 16 + ktn) * 64 + l) * 8];
            }
            bf16x8 af[4];
#pragma unroll
            for (int mb = 0; mb < 4; ++mb)
                af[mb] = *(const bf16x8*)&Al[buf][wm * 64 + mb * 16 + li][8 * g];
#pragma unroll
            for (int mb = 0; mb < 4; ++mb)
#pragma unroll
                for (int nb = 0; nb < 4; ++nb) acc[mb][nb] = MFMA16(af[mb], bw[nb], acc[mb][nb]);
            if (kt < 15) *(ushort8v*)&Al[buf ^ 1][arow][ak] = en;
            ldsbar();
#pragma unroll
            for (int nb = 0; nb < 4; ++nb) bw[nb] = bwn[nb];
        }

#pragma unroll
        for (int mb = 0; mb < 4; ++mb) {
#pragma unroll
            for (int nb = 0; nb < 4; ++nb) {
                const int col = vy * 256 + wn * 64 + nb * 16 + li;
                const int grow0 = row0 + wm * 64 + mb * 16 + 4 * g;
                const float bb = bv[col];
                ushort4v u;
#pragma unroll
                for (int r = 0; r < 4; ++r) u[r] = f2bf(acc[mb][nb][r] + bb);
                const int bbatch = grow0 >> 12, n = grow0 & 4095;
                *(ushort4v*)(Vt + ((size_t)bbatch * 512 + col) * 4096 + n) = u;
            }
        }
    }
#undef LOAD_E
}

// ---------------------------------------------------------------------------
// Shared attention segment body (v17 inner loop, parameterized by kv range).
// Processes cnt kv-tiles [kt0, kt0+cnt) of q-tile qcur, updating m/l/Of.
// ---------------------------------------------------------------------------
__device__ __forceinline__ void attn_segment(int kt0, int cnt, int qcur,
        const unsigned short* __restrict__ kgb, int krow, int kslot,
        const unsigned short* __restrict__ vbase,
        bf16x8 QA0, bf16x8 QA1,
        int w, int lane, int g, int li, int qrow,
        float& m_r, float& l_r, f32x4 (&Of)[4][2],
        unsigned short (*Kl)[64][64], unsigned short (*Pl)[64][76],
        float (*scl)[64], float (*dfl)[4])
{
    {   // prologue: stage tile kt0 into buf 0
        ushort8v v0 = *(const ushort8v*)(kgb + (size_t)kt0 * 4096);
        ushort8v v1 = *(const ushort8v*)(kgb + (size_t)kt0 * 4096 + 32 * 64);
        *(ushort8v*)&Kl[0][krow][kslot] = v0;
        *(ushort8v*)&Kl[0][krow + 32][kslot] = v1;
    }
    ldsbar();

    for (int j = 0; j < cnt; ++j) {
        const int buf = j & 1;
        const int kt = kt0 + j;
        const size_t kv0 = (size_t)kt * 64;
        const bool havenext = (j + 1 < cnt);

        const size_t kvn = (size_t)(kt0 + imin(j + 1, cnt - 1)) * 4096;
        ushort8v kn0 = *(const ushort8v*)(kgb + kvn);
        ushort8v kn1 = *(const ushort8v*)(kgb + kvn + 32 * 64);

        bf16x8 VA[2][2];
#pragma unroll
        for (int cf = 0; cf < 2; ++cf)
#pragma unroll
            for (int ks = 0; ks < 2; ++ks)
                VA[cf][ks] = *(const bf16x8*)(vbase + (size_t)cf * 16 * 4096 + kv0 + ks * 32);

        // ---- phase A: swapped QK^T (log2-domain scores) ----
        f32x4 S[4];
        {
            const unsigned short(*Kt)[64] = Kl[buf];
            __builtin_amdgcn_s_setprio(1);
#pragma unroll
            for (int cb = 0; cb < 4; ++cb) {
                const int row = cb * 16 + li;
                bf16x8 K0 = *(const bf16x8*)&Kt[row][((g) ^ (row & 7)) * 8];
                bf16x8 K1 = *(const bf16x8*)&Kt[row][((4 + g) ^ (row & 7)) * 8];
                f32x4 s = (f32x4)0.0f;
                s = MFMA16(K0, QA0, s);
                s = MFMA16(K1, QA1, s);
                S[cb] = s;
            }
            __builtin_amdgcn_s_setprio(0);
        }
        if (kt == qcur) {  // diagonal tile: mask kv > q
#pragma unroll
            for (int cb = 0; cb < 4; ++cb)
#pragma unroll
                for (int rr = 0; rr < 4; ++rr)
                    if (cb * 16 + 4 * g + rr > qrow) S[cb][rr] = -1e30f;
        }
        f32x4 m4 = S[0];
#pragma unroll
        for (int cb = 1; cb < 4; ++cb)
#pragma unroll
            for (int rr = 0; rr < 4; ++rr) m4[rr] = fmaxf(m4[rr], S[cb][rr]);
        const float pmL = fmaxf(fmaxf(m4[0], m4[1]), fmaxf(m4[2], m4[3]));

        const bool nore = __all(pmL - m_r <= 8.0f);
        float sc = 1.0f;
        if (!nore) {
            float pm = fmaxf(pmL, __shfl_xor(pmL, 16));
            pm = fmaxf(pm, __shfl_xor(pm, 32));
            const float mn = fmaxf(m_r, pm);
            sc = fexp2(m_r - mn);
            m_r = mn;
        }
        float rs = 0.0f;
#pragma unroll
        for (int cb = 0; cb < 4; ++cb) {
            bf16x4 pk;
#pragma unroll
            for (int rr = 0; rr < 4; ++rr) {
                const float pv = fexp2(S[cb][rr] - m_r);
                rs += pv;
                pk[rr] = (__bf16)pv;
            }
            *(bf16x4*)&Pl[buf][qrow][cb * 16 + 4 * g] = pk;
        }
        l_r = l_r * sc + rs;
        if (g == 0) scl[buf][qrow] = sc;
        if (lane == 0) dfl[buf][w] = nore ? 1.0f : 0.0f;

        if (havenext) {
            *(ushort8v*)&Kl[buf ^ 1][krow][kslot] = kn0;
            *(ushort8v*)&Kl[buf ^ 1][krow + 32][kslot] = kn1;
        }
        ldsbar();

        // ---- phase B: PV ----
        f32x4 df = *(const f32x4*)&dfl[buf][0];
        const bool allskip = (df[0] + df[1] + df[2] + df[3]) == 4.0f;
        __builtin_amdgcn_s_setprio(1);
#pragma unroll
        for (int qb = 0; qb < 4; ++qb) {
            bf16x8 PA0 = *(const bf16x8*)&Pl[buf][qb * 16 + li][8 * g];
            bf16x8 PA1 = *(const bf16x8*)&Pl[buf][qb * 16 + li][32 + 8 * g];
            if (!allskip) {
                f32x4 scv = *(const f32x4*)&scl[buf][qb * 16 + 4 * g];
#pragma unroll
                for (int cf = 0; cf < 2; ++cf)
#pragma unroll
                    for (int rr = 0; rr < 4; ++rr) Of[qb][cf][rr] *= scv[rr];
            }
#pragma unroll
            for (int cf = 0; cf < 2; ++cf) {
                f32x4 o = Of[qb][cf];
                o = MFMA16(PA0, VA[cf][0], o);
                o = MFMA16(PA1, VA[cf][1], o);
                Of[qb][cf] = o;
            }
        }
        __builtin_amdgcn_s_setprio(0);
    }
}

// ---------------------------------------------------------------------------
// attn_split: uniform-work blocks (all exactly 32-33 iterations).
// bid: half = bid&1 (0=A,1=B); rest: t (pair id), b, ch.
//  A: hi=63-t, kv tiles [0,33) -> partial to ws.
//  B: hi, kv tiles [33,64-t) -> partial to ws; reset; lo=t, kv [0,t] -> out.
// Partial record (per (half,pid)): O[64][128] f32 + m[64] + l[64] = 8320 f32.
// ---------------------------------------------------------------------------
__global__ __launch_bounds__(256) void attn_split(const unsigned short* __restrict__ Qb,
                                                  const unsigned short* __restrict__ Kb,
                                                  const unsigned short* __restrict__ Vt,
                                                  float* __restrict__ Pa,
                                                  float* __restrict__ out)
{
    __shared__ __align__(16) unsigned short Kl[2][64][64];
    __shared__ __align__(16) unsigned short Pl[2][64][76];
    __shared__ float scl[2][64];
    __shared__ __align__(16) float dfl[2][4];
    __shared__ float lsum_l[64];

    const int tid = threadIdx.x;
    const int w = tid >> 6, lane = tid & 63, g = lane >> 4, li = lane & 15;
    const int bid = blockIdx.x;
    const int half = bid & 1;
    const int rest = bid >> 1;               // [0,512)
    const int t = rest >> 4, b = (rest >> 2) & 3, ch = rest & 3;
    const int hi = 63 - t, lo = t;
    const int qrow = 16 * w + li;

    const int cglob = ch * 128 + w * 32 + li;
    const unsigned short* vbase = Vt + ((size_t)(b * 512 + cglob)) * 4096 + 8 * g;
    const int krow = tid >> 3, kch = tid & 7;
    const unsigned short* kgb = Kb + ((size_t)(b * 4096 + krow)) * 64 + kch * 8;
    const int kslot = (kch ^ (krow & 7)) * 8;

    float m_r = -INFINITY, l_r = 0.0f;
    f32x4 Of[4][2];
#pragma unroll
    for (int qb = 0; qb < 4; ++qb) { Of[qb][0] = (f32x4)0.0f; Of[qb][1] = (f32x4)0.0f; }

    float* rec = Pa + ((size_t)(half * 512 + rest)) * 8320;

    if (half == 0) {
        // ---- A: hi, kv [0,33) ----
        const unsigned short* qptr = Qb + ((size_t)(b * 4096 + hi * 64 + qrow)) * 64 + 8 * g;
        attn_segment(0, 33, hi, kgb, krow, kslot, vbase,
                     *(const bf16x8*)qptr, *(const bf16x8*)(qptr + 32),
                     w, lane, g, li, qrow, m_r, l_r, Of, Kl, Pl, scl, dfl);
        // write partial
        float lred = l_r + __shfl_xor(l_r, 16);
        lred += __shfl_xor(lred, 32);
#pragma unroll
        for (int qb = 0; qb < 4; ++qb)
#pragma unroll
            for (int cf = 0; cf < 2; ++cf)
#pragma unroll
                for (int rr = 0; rr < 4; ++rr)
                    rec[(size_t)(qb * 16 + 4 * g + rr) * 128 + (w * 32 + li) + cf * 16] = Of[qb][cf][rr];
        if (g == 0) { rec[8192 + qrow] = m_r; rec[8256 + qrow] = lred; }
    } else {
        // ---- B: hi kv [33, 64-t), then lo kv [0, t] ----
        const int cnt1 = 31 - t;   // may be 0 (t==31)
        if (cnt1 > 0) {
            const unsigned short* qptr = Qb + ((size_t)(b * 4096 + hi * 64 + qrow)) * 64 + 8 * g;
            attn_segment(33, cnt1, hi, kgb, krow, kslot, vbase,
                         *(const bf16x8*)qptr, *(const bf16x8*)(qptr + 32),
                         w, lane, g, li, qrow, m_r, l_r, Of, Kl, Pl, scl, dfl);
        }
        // write hi partial
        float lred = l_r + __shfl_xor(l_r, 16);
        lred += __shfl_xor(lred, 32);
#pragma unroll
        for (int qb = 0; qb < 4; ++qb)
#pragma unroll
            for (int cf = 0; cf < 2; ++cf)
#pragma unroll
                for (int rr = 0; rr < 4; ++rr)
                    rec[(size_t)(qb * 16 + 4 * g + rr) * 128 + (w * 32 + li) + cf * 16] = Of[qb][cf][rr];
        if (g == 0) { rec[8192 + qrow] = m_r; rec[8256 + qrow] = lred; }
        // reset state for lo tile
        m_r = -INFINITY; l_r = 0.0f;
#pragma unroll
        for (int qb = 0; qb < 4; ++qb) { Of[qb][0] = (f32x4)0.0f; Of[qb][1] = (f32x4)0.0f; }
        {
            const unsigned short* qptr = Qb + ((size_t)(b * 4096 + lo * 64 + qrow)) * 64 + 8 * g;
            attn_segment(0, t + 1, lo, kgb, krow, kslot, vbase,
                         *(const bf16x8*)qptr, *(const bf16x8*)(qptr + 32),
                         w, lane, g, li, qrow, m_r, l_r, Of, Kl, Pl, scl, dfl);
        }
        // direct epilogue for lo
        l_r += __shfl_xor(l_r, 16);
        l_r += __shfl_xor(l_r, 32);
        if (g == 0) lsum_l[qrow] = l_r;
        ldsbar();
        float* obase = out + (size_t)(b * 4096 + lo * 64 + 4 * g) * 512 + cglob;
#pragma unroll
        for (int qb = 0; qb < 4; ++qb) {
            f32x4 lv = *(const f32x4*)&lsum_l[qb * 16 + 4 * g];
#pragma unroll
            for (int cf = 0; cf < 2; ++cf)
#pragma unroll
                for (int rr = 0; rr < 4; ++rr)
                    obase[(size_t)(qb * 16 + rr) * 512 + cf * 16] = Of[qb][cf][rr] / lv[rr];
        }
    }
}

// ---------------------------------------------------------------------------
// merge_kernel: combine A/B hi partials (flash merge, log2 domain) -> out.
// ---------------------------------------------------------------------------
__global__ __launch_bounds__(256) void merge_kernel(const float* __restrict__ Pa,
                                                    float* __restrict__ out)
{
    const int pid = blockIdx.x;  // [0,512)
    const int t = pid >> 4, b = (pid >> 2) & 3, ch = pid & 3;
    const int hi = 63 - t;
    const float* A = Pa + (size_t)pid * 8320;
    const float* B = Pa + (size_t)(512 + pid) * 8320;
    const int tid = threadIdx.x;
#pragma unroll
    for (int k = 0; k < 8; ++k) {
        const int vidx = k * 256 + tid;       // f32x4 index over 64x128
        const int row = vidx >> 5;
        const int col4 = (vidx & 31) * 4;
        const float ma = A[8192 + row], mb = B[8192 + row];
        const float mF = fmaxf(ma, mb);
        const float aA = fexp2(ma - mF), aB = fexp2(mb - mF);
        const float l = aA * A[8256 + row] + aB * B[8256 + row];
        f32x4 oa = *(const f32x4*)&A[(size_t)row * 128 + col4];
        f32x4 ob = *(const f32x4*)&B[(size_t)row * 128 + col4];
        f32x4 r;
#pragma unroll
        for (int j = 0; j < 4; ++j) r[j] = (aA * oa[j] + aB * ob[j]) / l;
        *(f32x4*)&out[((size_t)(b * 4096 + hi * 64 + row)) * 512 + ch * 128 + col4] = r;
    }
}

// ---------------------------------------------------------------------------
// Fallback: v17 attention (best measured monolithic: 93.3 us).
// ---------------------------------------------------------------------------
__global__ __launch_bounds__(256) void attn_kernel(const unsigned short* __restrict__ Qb,
                                                   const unsigned short* __restrict__ Kb,
                                                   const unsigned short* __restrict__ Vt,
                                                   float* __restrict__ out)
{
    __shared__ __align__(16) unsigned short Kl[2][64][64];
    __shared__ __align__(16) unsigned short Pl[2][64][76];
    __shared__ float scl[2][64];
    __shared__ __align__(16) float dfl[2][4];
    __shared__ float lsum_l[64];

    const int tid = threadIdx.x;
    const int w = tid >> 6, lane = tid & 63, g = lane >> 4, li = lane & 15;
    const int bid = blockIdx.x;
    const int x = bid >> 4, b = (bid >> 2) & 3, ch = bid & 3;
    const int k4 = x >> 4, r4 = x & 15;
    const int qt = (k4 == 0) ? r4 : (k4 == 1) ? (63 - r4) : (k4 == 2) ? (16 + r4) : (47 - r4);
    const int q0 = qt * 64;
    const int qrow = 16 * w + li;

    const int cglob = ch * 128 + w * 32 + li;
    const unsigned short* vbase = Vt + ((size_t)(b * 512 + cglob)) * 4096 + 8 * g;
    const int krow = tid >> 3, kch = tid & 7;
    const unsigned short* kgb = Kb + ((size_t)(b * 4096 + krow)) * 64 + kch * 8;
    const int kslot = (kch ^ (krow & 7)) * 8;

    float m_r = -INFINITY, l_r = 0.0f;
    f32x4 Of[4][2];
#pragma unroll
    for (int qb = 0; qb < 4; ++qb) { Of[qb][0] = (f32x4)0.0f; Of[qb][1] = (f32x4)0.0f; }

    const unsigned short* qptr = Qb + ((size_t)(b * 4096 + q0 + qrow)) * 64 + 8 * g;
    attn_segment(0, qt + 1, qt, kgb, krow, kslot, vbase,
                 *(const bf16x8*)qptr, *(const bf16x8*)(qptr + 32),
                 w, lane, g, li, qrow, m_r, l_r, Of, Kl, Pl, scl, dfl);

    l_r += __shfl_xor(l_r, 16);
    l_r += __shfl_xor(l_r, 32);
    if (g == 0) lsum_l[qrow] = l_r;
    ldsbar();

    float* obase = out + (size_t)(b * 4096 + q0 + 4 * g) * 512 + cglob;
#pragma unroll
    for (int qb = 0; qb < 4; ++qb) {
        f32x4 lv = *(const f32x4*)&lsum_l[qb * 16 + 4 * g];
#pragma unroll
        for (int cf = 0; cf < 2; ++cf)
#pragma unroll
            for (int rr = 0; rr < 4; ++rr)
                obase[(size_t)(qb * 16 + rr) * 512 + cf * 16] = Of[qb][cf][rr] / lv[rr];
    }
}

// ---------------------------------------------------------------------------
extern "C" void kernel_launch(void* const* d_in, const int* in_sizes, int n_in,
                              void* d_out, int out_size, void* d_ws, size_t ws_size,
                              hipStream_t stream)
{
    (void)in_sizes; (void)n_in; (void)out_size;
    const float* E  = (const float*)d_in[0];
    const float* wq = (const float*)d_in[2];
    const float* bq = (const float*)d_in[3];
    const float* wk = (const float*)d_in[4];
    const float* bk = (const float*)d_in[5];
    const float* wv = (const float*)d_in[6];
    const float* bv = (const float*)d_in[7];

    const size_t qk_elems = (size_t)4 * 4096 * 64;
    const size_t vt_elems = (size_t)4 * 512 * 4096;

    unsigned short* Qb  = (unsigned short*)d_ws;        // [4][4096][64] bf16 (x0.125xlog2e)
    unsigned short* Kb  = Qb + qk_elems;                // [4][4096][64] bf16
    unsigned short* Vt  = Kb + qk_elems;                // [4][512][4096] bf16 (transposed)
    unsigned short* Fqk = Vt + vt_elems;                // frag-ordered wq|wk
    unsigned short* Fv  = Fqk + (size_t)8192 * 8;       // frag-ordered wv
    float* Pa = (float*)(Fv + (size_t)32768 * 8);       // A/B hi partials
    float* out = (float*)d_out;

    const size_t base_bytes = (2 * qk_elems + vt_elems + (size_t)8192 * 8 + (size_t)32768 * 8) * 2;
    const size_t need_split = base_bytes + (size_t)1024 * 8320 * 4;

    prep_w<<<dim3(160), 256, 0, stream>>>(wq, wk, wv, Fqk, Fv);
    proj_kernel<<<dim3(128, 3), 512, 0, stream>>>(E, Fqk, Fv, bq, bk, bv, Qb, Kb, Vt);
    if (ws_size >= need_split) {
        attn_split<<<dim3(1024), 256, 0, stream>>>(Qb, Kb, Vt, Pa, out);
        merge_kernel<<<dim3(512), 256, 0, stream>>>(Pa, out);
    } else {
        attn_kernel<<<dim3(1024), 256, 0, stream>>>(Qb, Kb, Vt, out);
    }
}

// Round 21
// 115.790 us; speedup vs baseline: 1.8002x; 1.8002x over previous
//
#include <hip/hip_runtime.h>
#include <hip/hip_bf16.h>

typedef float f32x4 __attribute__((ext_vector_type(4)));
typedef __bf16 bf16x8 __attribute__((ext_vector_type(8)));
typedef __bf16 bf16x4 __attribute__((ext_vector_type(4)));
typedef unsigned short ushort4v __attribute__((ext_vector_type(4)));
typedef unsigned short ushort8v __attribute__((ext_vector_type(8)));

#define MFMA16(a, b, c) __builtin_amdgcn_mfma_f32_16x16x32_bf16((a), (b), (c), 0, 0, 0)

__device__ __forceinline__ unsigned short f2bf(float f) {
    union { float f; unsigned int u; } v; v.f = f;
    unsigned int r = (v.u + 0x7fffu + ((v.u >> 16) & 1u)) >> 16;  // RNE
    return (unsigned short)r;
}
__device__ __forceinline__ int imin(int a, int b) { return a < b ? a : b; }
__device__ __forceinline__ float fexp2(float x) {  // raw v_exp_f32 (2^x)
    float r; asm("v_exp_f32 %0, %1" : "=v"(r) : "v"(x)); return r;
}

// LDS-only barrier: flush this wave's LDS ops, then s_barrier (no vmcnt drain).
__device__ __forceinline__ void ldsbar() {
    asm volatile("s_waitcnt lgkmcnt(0)" ::: "memory");
    __builtin_amdgcn_s_barrier();
}

// ---------------------------------------------------------------------------
// prep_w: W -> bf16 in MFMA-fragment order (round-15, measured good).
// ---------------------------------------------------------------------------
__global__ __launch_bounds__(256) void prep_w(const float* __restrict__ wq,
                                              const float* __restrict__ wk,
                                              const float* __restrict__ wv,
                                              unsigned short* __restrict__ Fqk,
                                              unsigned short* __restrict__ Fv)
{
    const int t = blockIdx.x * 256 + threadIdx.x;
    if (t < 8192) {
        const int lane = t & 63, kt = (t >> 6) & 15, ct = t >> 10;
        const int g = lane >> 4, li = lane & 15;
        const int c = ct * 16 + li;
        const int k0 = kt * 32 + g * 8;
        ushort8v u;
        if (c < 64) {
#pragma unroll
            for (int j = 0; j < 8; ++j) u[j] = f2bf(wq[(size_t)(k0 + j) * 64 + c]);
        } else {
#pragma unroll
            for (int j = 0; j < 8; ++j) u[j] = f2bf(wk[(size_t)(k0 + j) * 64 + (c - 64)]);
        }
        *(ushort8v*)&Fqk[(size_t)t * 8] = u;
    } else {
        const int t2 = t - 8192;
        const int lane = t2 & 63, kt = (t2 >> 6) & 15, ct = t2 >> 10;
        const int g = lane >> 4, li = lane & 15;
        const int c = ct * 16 + li;
        const int k0 = kt * 32 + g * 8;
        ushort8v u;
#pragma unroll
        for (int j = 0; j < 8; ++j) u[j] = f2bf(wv[(size_t)(k0 + j) * 512 + c]);
        *(ushort8v*)&Fv[(size_t)t2 * 8] = u;
    }
}

// ---------------------------------------------------------------------------
// Projection v2 (round-15, measured ~18-20 us): no B-LDS, A dbuf, 1 ldsbar/kt.
// ---------------------------------------------------------------------------
__global__ __launch_bounds__(512) void proj_kernel(const float* __restrict__ E,
        const unsigned short* __restrict__ Fqk, const unsigned short* __restrict__ Fv,
        const float* __restrict__ bq, const float* __restrict__ bk, const float* __restrict__ bv,
        unsigned short* __restrict__ Qb, unsigned short* __restrict__ Kb,
        unsigned short* __restrict__ Vt)
{
    __shared__ __align__(16) unsigned short Al[2][128][40];

    const int tid = threadIdx.x;
    const int w = tid >> 6, l = tid & 63, g = l >> 4, li = l & 15;
    const int wm = w >> 2, wn = w & 3;
    const int bx = blockIdx.x, by = blockIdx.y;
    const int row0 = bx * 128;
    const int arow = tid >> 2, ak = (tid & 3) * 8;
    const float* ebase = &E[(size_t)(row0 + arow) * 512 + ak];
    const float QSCALE = 0.125f * 1.4426950408889634f;  // 1/8 * log2(e)

#define LOAD_E(kt, dst)                                                          \
    {                                                                            \
        const float* ep = ebase + (kt) * 32;                                     \
        f32x4 v0 = *(const f32x4*)ep;                                            \
        f32x4 v1 = *(const f32x4*)(ep + 4);                                      \
        _Pragma("unroll")                                                        \
        for (int j = 0; j < 4; ++j) { dst[j] = f2bf(v0[j]); dst[4 + j] = f2bf(v1[j]); } \
    }

    if (by == 0) {
        f32x4 acc[4][2];
#pragma unroll
        for (int mb = 0; mb < 4; ++mb)
#pragma unroll
            for (int nb = 0; nb < 2; ++nb) acc[mb][nb] = (f32x4)0.0f;

        bf16x8 bw[2], bwn[2];
        {
            ushort8v e0; LOAD_E(0, e0);
            *(ushort8v*)&Al[0][arow][ak] = e0;
#pragma unroll
            for (int nb = 0; nb < 2; ++nb) {
                const int ct = wn * 2 + nb;
                bw[nb] = *(const bf16x8*)&Fqk[((size_t)(ct * 16 + 0) * 64 + l) * 8];
            }
        }
        ldsbar();

        for (int kt = 0; kt < 16; ++kt) {
            const int buf = kt & 1;
            ushort8v en;
            if (kt < 15) LOAD_E(kt + 1, en);
            const int ktn = imin(kt + 1, 15);
#pragma unroll
            for (int nb = 0; nb < 2; ++nb) {
                const int ct = wn * 2 + nb;
                bwn[nb] = *(const bf16x8*)&Fqk[((size_t)(ct * 16 + ktn) * 64 + l) * 8];
            }
            bf16x8 af[4];
#pragma unroll
            for (int mb = 0; mb < 4; ++mb)
                af[mb] = *(const bf16x8*)&Al[buf][wm * 64 + mb * 16 + li][8 * g];
#pragma unroll
            for (int mb = 0; mb < 4; ++mb)
#pragma unroll
                for (int nb = 0; nb < 2; ++nb) acc[mb][nb] = MFMA16(af[mb], bw[nb], acc[mb][nb]);
            if (kt < 15) *(ushort8v*)&Al[buf ^ 1][arow][ak] = en;
            ldsbar();
            bw[0] = bwn[0]; bw[1] = bwn[1];
        }

#pragma unroll
        for (int mb = 0; mb < 4; ++mb) {
#pragma unroll
            for (int nb = 0; nb < 2; ++nb) {
                const int coll = wn * 32 + nb * 16 + li;
                const int grow0 = row0 + wm * 64 + mb * 16 + 4 * g;
                if (coll < 64) {
                    const float bb = bq[coll];
#pragma unroll
                    for (int r = 0; r < 4; ++r)
                        Qb[(size_t)(grow0 + r) * 64 + coll] = f2bf((acc[mb][nb][r] + bb) * QSCALE);
                } else {
                    const float bb = bk[coll - 64];
#pragma unroll
                    for (int r = 0; r < 4; ++r)
                        Kb[(size_t)(grow0 + r) * 64 + (coll - 64)] = f2bf(acc[mb][nb][r] + bb);
                }
            }
        }
    } else {
        const int vy = by - 1;
        f32x4 acc[4][4];
#pragma unroll
        for (int mb = 0; mb < 4; ++mb)
#pragma unroll
            for (int nb = 0; nb < 4; ++nb) acc[mb][nb] = (f32x4)0.0f;

        bf16x8 bw[4], bwn[4];
        {
            ushort8v e0; LOAD_E(0, e0);
            *(ushort8v*)&Al[0][arow][ak] = e0;
#pragma unroll
            for (int nb = 0; nb < 4; ++nb) {
                const int ct = vy * 16 + wn * 4 + nb;
                bw[nb] = *(const bf16x8*)&Fv[((size_t)(ct * 16 + 0) * 64 + l) * 8];
            }
        }
        ldsbar();

        for (int kt = 0; kt < 16; ++kt) {
            const int buf = kt & 1;
            ushort8v en;
            if (kt < 15) LOAD_E(kt + 1, en);
            const int ktn = imin(kt + 1, 15);
#pragma unroll
            for (int nb = 0; nb < 4; ++nb) {
                const int ct = vy * 16 + wn * 4 + nb;
                bwn[nb] = *(const bf16x8*)&Fv[((size_t)(ct * 16 + ktn) * 64 + l) * 8];
            }
            bf16x8 af[4];
#pragma unroll
            for (int mb = 0; mb < 4; ++mb)
                af[mb] = *(const bf16x8*)&Al[buf][wm * 64 + mb * 16 + li][8 * g];
#pragma unroll
            for (int mb = 0; mb < 4; ++mb)
#pragma unroll
                for (int nb = 0; nb < 4; ++nb) acc[mb][nb] = MFMA16(af[mb], bw[nb], acc[mb][nb]);
            if (kt < 15) *(ushort8v*)&Al[buf ^ 1][arow][ak] = en;
            ldsbar();
#pragma unroll
            for (int nb = 0; nb < 4; ++nb) bw[nb] = bwn[nb];
        }

#pragma unroll
        for (int mb = 0; mb < 4; ++mb) {
#pragma unroll
            for (int nb = 0; nb < 4; ++nb) {
                const int col = vy * 256 + wn * 64 + nb * 16 + li;
                const int grow0 = row0 + wm * 64 + mb * 16 + 4 * g;
                const float bb = bv[col];
                ushort4v u;
#pragma unroll
                for (int r = 0; r < 4; ++r) u[r] = f2bf(acc[mb][nb][r] + bb);
                const int bbatch = grow0 >> 12, n = grow0 & 4095;
                *(ushort4v*)(Vt + ((size_t)bbatch * 512 + col) * 4096 + n) = u;
            }
        }
    }
#undef LOAD_E
}

// ---------------------------------------------------------------------------
// Causal flash attention, v17 (best measured: 93.3 us attn / 115.8 us total).
// 4-wave blocks (64q x 128c), wave-local softmax, one non-draining barrier
// per iter, K LDS XOR double-buffer, V reg loads (same-iteration, measured
// optimal vs deeper prefetch in r18 A/B), [76] pad (0 conflicts), exp2-native
// log2-domain softmax, T13 defer-max with block-uniform rescale skip, lazy
// l/pm reductions (epilogue-only cross-g reduce), tau-balanced 1024-block
// grid (4 blocks/CU = 4 independent latency chains).
// ---------------------------------------------------------------------------
__global__ __launch_bounds__(256) void attn_kernel(const unsigned short* __restrict__ Qb,
                                                   const unsigned short* __restrict__ Kb,
                                                   const unsigned short* __restrict__ Vt,
                                                   float* __restrict__ out)
{
    __shared__ __align__(16) unsigned short Kl[2][64][64];  // [buf][kv][d], chunk^row swizzle
    __shared__ __align__(16) unsigned short Pl[2][64][76];  // [buf][q][kv+pad]
    __shared__ float scl[2][64];
    __shared__ __align__(16) float dfl[2][4];               // per-wave defer flags
    __shared__ float lsum_l[64];

    const int tid = threadIdx.x;
    const int w = tid >> 6, lane = tid & 63, g = lane >> 4, li = lane & 15;
    const int bid = blockIdx.x;
    const int x = bid >> 4, b = (bid >> 2) & 3, ch = bid & 3;
    const int k4 = x >> 4, r4 = x & 15;
    // tau: co-resident {r,r+16,r+32,r+48} -> qts {r, 63-r, 16+r, 47-r}
    const int qt = (k4 == 0) ? r4 : (k4 == 1) ? (63 - r4) : (k4 == 2) ? (16 + r4) : (47 - r4);
    const int q0 = qt * 64;
    const int niter = qt + 1;
    const int qrow = 16 * w + li;   // this wave's q rows (tile-local)

    const unsigned short* qptr = Qb + ((size_t)(b * 4096 + q0 + qrow)) * 64 + 8 * g;
    const bf16x8 QA0 = *(const bf16x8*)qptr;
    const bf16x8 QA1 = *(const bf16x8*)(qptr + 32);

    float m_r = -INFINITY, l_r = 0.0f;   // l_r: PER-LANE partial (g-group share)
    f32x4 Of[4][2];
#pragma unroll
    for (int qb = 0; qb < 4; ++qb) { Of[qb][0] = (f32x4)0.0f; Of[qb][1] = (f32x4)0.0f; }

    const int cglob = ch * 128 + w * 32 + li;
    const unsigned short* vbase = Vt + ((size_t)(b * 512 + cglob)) * 4096 + 8 * g;

    // K staging: 256 threads, each stages rows krow and krow+32, chunk kch
    const int krow = tid >> 3, kch = tid & 7;
    const unsigned short* kgb = Kb + ((size_t)(b * 4096 + krow)) * 64 + kch * 8;
    const int kslot = (kch ^ (krow & 7)) * 8;

    {   // prologue: stage tile 0 into buf 0
        ushort8v v0 = *(const ushort8v*)(kgb);
        ushort8v v1 = *(const ushort8v*)(kgb + 32 * 64);
        *(ushort8v*)&Kl[0][krow][kslot] = v0;
        *(ushort8v*)&Kl[0][krow + 32][kslot] = v1;
    }
    ldsbar();

    for (int j = 0; j < niter; ++j) {
        const int buf = j & 1;
        const size_t kv0 = (size_t)j * 64;
        const bool havenext = (j + 1 < niter);

        // next-tile K global loads (land into other buf before the barrier)
        const size_t kvn = (size_t)imin(j + 1, qt) * 4096;
        ushort8v kn0 = *(const ushort8v*)(kgb + kvn);
        ushort8v kn1 = *(const ushort8v*)(kgb + kvn + 32 * 64);

        // this tile's V loads (consumed in phase B)
        bf16x8 VA[2][2];
#pragma unroll
        for (int cf = 0; cf < 2; ++cf)
#pragma unroll
            for (int ks = 0; ks < 2; ++ks)
                VA[cf][ks] = *(const bf16x8*)(vbase + (size_t)cf * 16 * 4096 + kv0 + ks * 32);

        // ---- phase A: swapped QK^T (log2-domain scores) ----
        f32x4 S[4];
        {
            const unsigned short(*Kt)[64] = Kl[buf];
            __builtin_amdgcn_s_setprio(1);
#pragma unroll
            for (int cb = 0; cb < 4; ++cb) {
                const int row = cb * 16 + li;
                bf16x8 K0 = *(const bf16x8*)&Kt[row][((g) ^ (row & 7)) * 8];
                bf16x8 K1 = *(const bf16x8*)&Kt[row][((4 + g) ^ (row & 7)) * 8];
                f32x4 s = (f32x4)0.0f;
                s = MFMA16(K0, QA0, s);   // A = K, B = Q  ->  D = S^T
                s = MFMA16(K1, QA1, s);
                S[cb] = s;
            }
            __builtin_amdgcn_s_setprio(0);
        }
        if (j == qt) {  // diagonal tile: mask kv > q
#pragma unroll
            for (int cb = 0; cb < 4; ++cb)
#pragma unroll
                for (int rr = 0; rr < 4; ++rr)
                    if (cb * 16 + 4 * g + rr > qrow) S[cb][rr] = -1e30f;
        }
        // wave-local online softmax; defer check on PER-LANE maxima (equivalent)
        f32x4 m4 = S[0];
#pragma unroll
        for (int cb = 1; cb < 4; ++cb)
#pragma unroll
            for (int rr = 0; rr < 4; ++rr) m4[rr] = fmaxf(m4[rr], S[cb][rr]);
        const float pmL = fmaxf(fmaxf(m4[0], m4[1]), fmaxf(m4[2], m4[3]));

        const bool nore = __all(pmL - m_r <= 8.0f);
        float sc = 1.0f;
        if (!nore) {  // rare path: full cross-g reduce + m update
            float pm = fmaxf(pmL, __shfl_xor(pmL, 16));
            pm = fmaxf(pm, __shfl_xor(pm, 32));
            const float mn = fmaxf(m_r, pm);
            sc = fexp2(m_r - mn);
            m_r = mn;
        }
        float rs = 0.0f;
#pragma unroll
        for (int cb = 0; cb < 4; ++cb) {
            bf16x4 pk;
#pragma unroll
            for (int rr = 0; rr < 4; ++rr) {
                const float pv = fexp2(S[cb][rr] - m_r);
                rs += pv;
                pk[rr] = (__bf16)pv;
            }
            *(bf16x4*)&Pl[buf][qrow][cb * 16 + 4 * g] = pk;  // ds_write_b64
        }
        l_r = l_r * sc + rs;            // per-lane partial; reduced at epilogue
        if (g == 0) scl[buf][qrow] = sc;
        if (lane == 0) dfl[buf][w] = nore ? 1.0f : 0.0f;

        // land next K tile into the other buffer
        if (havenext) {
            *(ushort8v*)&Kl[buf ^ 1][krow][kslot] = kn0;
            *(ushort8v*)&Kl[buf ^ 1][krow + 32][kslot] = kn1;
        }
        ldsbar();  // the single per-iteration barrier (LDS-only)

        // ---- phase B: PV for this wave's 32 cols, all 64 q rows ----
        f32x4 df = *(const f32x4*)&dfl[buf][0];
        const bool allskip = (df[0] + df[1] + df[2] + df[3]) == 4.0f;
        __builtin_amdgcn_s_setprio(1);
#pragma unroll
        for (int qb = 0; qb < 4; ++qb) {
            bf16x8 PA0 = *(const bf16x8*)&Pl[buf][qb * 16 + li][8 * g];
            bf16x8 PA1 = *(const bf16x8*)&Pl[buf][qb * 16 + li][32 + 8 * g];
            if (!allskip) {
                f32x4 scv = *(const f32x4*)&scl[buf][qb * 16 + 4 * g];
#pragma unroll
                for (int cf = 0; cf < 2; ++cf)
#pragma unroll
                    for (int rr = 0; rr < 4; ++rr) Of[qb][cf][rr] *= scv[rr];
            }
#pragma unroll
            for (int cf = 0; cf < 2; ++cf) {
                f32x4 o = Of[qb][cf];
                o = MFMA16(PA0, VA[cf][0], o);
                o = MFMA16(PA1, VA[cf][1], o);
                Of[qb][cf] = o;
            }
        }
        __builtin_amdgcn_s_setprio(0);
    }

    // epilogue: reduce the per-lane l partials across the 4 g-groups (once)
    l_r += __shfl_xor(l_r, 16);
    l_r += __shfl_xor(l_r, 32);
    if (g == 0) lsum_l[qrow] = l_r;
    ldsbar();

    float* obase = out + (size_t)(b * 4096 + q0 + 4 * g) * 512 + cglob;
#pragma unroll
    for (int qb = 0; qb < 4; ++qb) {
        f32x4 lv = *(const f32x4*)&lsum_l[qb * 16 + 4 * g];
#pragma unroll
        for (int cf = 0; cf < 2; ++cf)
#pragma unroll
            for (int rr = 0; rr < 4; ++rr)
                obase[(size_t)(qb * 16 + rr) * 512 + cf * 16] = Of[qb][cf][rr] / lv[rr];
    }
}

// ---------------------------------------------------------------------------
extern "C" void kernel_launch(void* const* d_in, const int* in_sizes, int n_in,
                              void* d_out, int out_size, void* d_ws, size_t ws_size,
                              hipStream_t stream)
{
    (void)in_sizes; (void)n_in; (void)out_size; (void)ws_size;
    const float* E  = (const float*)d_in[0];
    const float* wq = (const float*)d_in[2];
    const float* bq = (const float*)d_in[3];
    const float* wk = (const float*)d_in[4];
    const float* bk = (const float*)d_in[5];
    const float* wv = (const float*)d_in[6];
    const float* bv = (const float*)d_in[7];

    const size_t qk_elems = (size_t)4 * 4096 * 64;
    const size_t vt_elems = (size_t)4 * 512 * 4096;

    unsigned short* Qb  = (unsigned short*)d_ws;        // [4][4096][64] bf16 (x0.125xlog2e)
    unsigned short* Kb  = Qb + qk_elems;                // [4][4096][64] bf16
    unsigned short* Vt  = Kb + qk_elems;                // [4][512][4096] bf16 (transposed)
    unsigned short* Fqk = Vt + vt_elems;                // frag-ordered wq|wk
    unsigned short* Fv  = Fqk + (size_t)8192 * 8;       // frag-ordered wv
    float* out = (float*)d_out;

    prep_w<<<dim3(160), 256, 0, stream>>>(wq, wk, wv, Fqk, Fv);
    proj_kernel<<<dim3(128, 3), 512, 0, stream>>>(E, Fqk, Fv, bq, bk, bv, Qb, Kb, Vt);
    attn_kernel<<<dim3(1024), 256, 0, stream>>>(Qb, Kb, Vt, out);
}